// Round 7
// baseline (153.233 us; speedup 1.0000x reference)
//
#include <hip/hip_runtime.h>

#define NPI 50      // nodes per inner graph
#define EPI 400     // edges per inner graph
#define NPO 125     // nodes per outer graph
#define EPO 1000    // edges per outer graph
#define N_IN 100000
#define N_OUT 2000
#define NB 16       // batch graphs
#define NC 10

typedef _Float16 half_t;
typedef _Float16 f16x8 __attribute__((ext_vector_type(8)));
typedef float f32x4 __attribute__((ext_vector_type(4)));

#define MFMA(a, b, c) __builtin_amdgcn_mfma_f32_16x16x32_f16(a, b, c, 0, 0, 0)

// Swizzled LDS helpers (used by k_outer), as in r4.
__device__ __forceinline__ f16x8 lds_ld8(const half_t* base, int row, int k, int strideB) {
    return *(const f16x8*)((const char*)base + row * strideB + ((k * 2) ^ ((row & 7) << 4)));
}
__device__ __forceinline__ void lds_st1(half_t* base, int row, int col, int strideB, float v) {
    *(half_t*)((char*)base + row * strideB + ((col * 2) ^ ((row & 7) << 4))) = (half_t)v;
}
__device__ __forceinline__ void lds_st1h(half_t* base, int row, int col, int strideB, half_t v) {
    *(half_t*)((char*)base + row * strideB + ((col * 2) ^ ((row & 7) << 4))) = v;
}
__device__ __forceinline__ void lds_st8(half_t* base, int row, int k, int strideB, f16x8 v) {
    *(f16x8*)((char*)base + row * strideB + ((k * 2) ^ ((row & 7) << 4))) = v;
}

// ---------------------------------------------------------------------------
// k_pre: blocks 0..383 convert W1..W6 -> transposed f16; blocks 384..399 build
// dense outer adjacency Â_outer [16][128][128] f16 (row-major). [r4-proven]
// ---------------------------------------------------------------------------
__global__ __launch_bounds__(256) void k_pre(
    const float* __restrict__ W1, const float* __restrict__ W2,
    const float* __restrict__ W3, const float* __restrict__ W4,
    const float* __restrict__ W5, const float* __restrict__ W6,
    half_t* __restrict__ WT1, half_t* __restrict__ WT2,
    half_t* __restrict__ WT3, half_t* __restrict__ WT4,
    half_t* __restrict__ WT5, half_t* __restrict__ WT6,
    const float* __restrict__ ew, const int* __restrict__ esrc,
    const int* __restrict__ edst, half_t* __restrict__ Aout)
{
    __shared__ float Af[NPO * NPO];
    __shared__ int cO[NPO], cI[NPO];
    __shared__ float rso[NPO], rsi[NPO];
    const int t = threadIdx.x;

    if (blockIdx.x < 384) {
        int i = blockIdx.x * 256 + t;
        const float* src; half_t* dst; int K;
        if      (i < 8192)  { src = W1; dst = WT1; K = 64; }
        else if (i < 24576) { src = W2; dst = WT2; K = 128; i -= 8192; }
        else if (i < 49152) { src = W3; dst = WT3; K = 192; i -= 24576; }
        else if (i < 65536) { src = W4; dst = WT4; K = 128; i -= 49152; }
        else if (i < 81920) { src = W5; dst = WT5; K = 128; i -= 65536; }
        else                { src = W6; dst = WT6; K = 128; i -= 81920; }
        int c = i & 127, k = i >> 7;
        dst[c * K + k] = (half_t)src[k * 128 + c];
        return;
    }

    const int g = blockIdx.x - 384;
    const int nb = g * NPO, eb = g * EPO;
    for (int i = t; i < NPO * NPO; i += 256) Af[i] = 0.f;
    if (t < NPO) { cO[t] = 0; cI[t] = 0; }
    __syncthreads();
    for (int e = t; e < EPO; e += 256) {
        int s = esrc[eb + e] - nb, d = edst[eb + e] - nb;
        atomicAdd(&Af[d * NPO + s], ew[eb + e]);
        atomicAdd(&cO[s], 1); atomicAdd(&cI[d], 1);
    }
    __syncthreads();
    if (t < NPO) {
        rso[t] = rsqrtf((float)max(cO[t], 1));
        rsi[t] = rsqrtf((float)max(cI[t], 1));
    }
    __syncthreads();
    for (int i = t; i < 128 * 16; i += 256) {
        int d = i >> 4, s0 = (i & 15) * 8;
        f16x8 v;
        #pragma unroll
        for (int j = 0; j < 8; j++) {
            int s = s0 + j;
            float x = (d < NPO && s < NPO) ? Af[d * NPO + s] * rsi[d] * rso[s] : 0.f;
            v[j] = (half_t)x;
        }
        *(f16x8*)&Aout[(size_t)g * 16384 + d * 128 + s0] = v;
    }
}

// ---------------------------------------------------------------------------
// k_adjI: per-graph inner Â (64x64 zero-padded, normalized) -> global f16.
// 2000 blocks x 256. Plain LDS layout, 3 barriers, ~17KB LDS.
// ---------------------------------------------------------------------------
__global__ __launch_bounds__(256) void k_adjI(
    const float* __restrict__ ew, const int* __restrict__ esrc,
    const int* __restrict__ edst, half_t* __restrict__ AinG)
{
    __shared__ float Af[64 * 64];
    __shared__ int cO[64], cI[64];
    const int g = blockIdx.x, t = threadIdx.x;
    const int nb = g * NPI, eb = g * EPI;

    int s0e, d0e; float w0e;
    { int e = eb + t; s0e = esrc[e] - nb; d0e = edst[e] - nb; w0e = ew[e]; }
    int s1e = 0, d1e = 0; float w1e = 0.f;
    const bool e1v = (t + 256 < EPI);
    if (e1v) { int e = eb + t + 256; s1e = esrc[e] - nb; d1e = edst[e] - nb; w1e = ew[e]; }

    if (t < 64) { cO[t] = 0; cI[t] = 0; }
    for (int i = t; i < 4096; i += 256) Af[i] = 0.f;
    __syncthreads();
    atomicAdd(&Af[d0e * 64 + s0e], w0e);
    atomicAdd(&cO[s0e], 1); atomicAdd(&cI[d0e], 1);
    if (e1v) {
        atomicAdd(&Af[d1e * 64 + s1e], w1e);
        atomicAdd(&cO[s1e], 1); atomicAdd(&cI[d1e], 1);
    }
    __syncthreads();
    // 512 chunks of 8: id = t + j*256 -> row = id>>3, k0 = (id&7)*8
    #pragma unroll
    for (int j = 0; j < 2; j++) {
        int id = t + j * 256;
        int row = id >> 3, k0 = (id & 7) * 8;
        float rsi_l = rsqrtf((float)max(cI[row], 1));
        f16x8 v;
        #pragma unroll
        for (int jj = 0; jj < 8; jj++)
            v[jj] = (half_t)(Af[row * 64 + k0 + jj] * rsi_l *
                             rsqrtf((float)max(cO[k0 + jj], 1)));
        *(f16x8*)&AinG[(size_t)g * 4096 + row * 64 + k0] = v;
    }
}

// ---------------------------------------------------------------------------
// k_gemmT: Y^T = (A @ WT^T)^T stored per graph as [2000][128][64].
// M = 128000 padded rows (64/graph); padded/out-of-range rows clamp to a real
// source row (finite garbage; killed later by Â's zero columns).
// F32IN: A is f32 (X); else f16 (h1, real-node indexed [100000][128]).
// ---------------------------------------------------------------------------
template <int K, bool F32IN>
__global__ __launch_bounds__(256) void k_gemmT(
    const void* __restrict__ Ain, const half_t* __restrict__ BT,
    half_t* __restrict__ YT)
{
    const int t = threadIdx.x, w = t >> 6, l = t & 63;
    const int lr = l & 15, lk = l >> 4;
    const int r0 = blockIdx.x * 128 + w * 32;

    // padded row -> real source row
    const int ra = r0 + lr, rb = r0 + 16 + lr;
    const int xra = (ra >> 6) * 50 + min(ra & 63, 49);
    const int xrb = (rb >> 6) * 50 + min(rb & 63, 49);

    f32x4 acc[2][8] = {};
    for (int ks = 0; ks < K / 32; ks++) {
        const int ko = ks * 32 + lk * 8;
        f16x8 a0, a1;
        if constexpr (F32IN) {
            const float* A = (const float*)Ain;
            const float* pa = &A[(size_t)xra * K + ko];
            const float* pb = &A[(size_t)xrb * K + ko];
            #pragma unroll
            for (int j = 0; j < 8; j++) { a0[j] = (half_t)pa[j]; a1[j] = (half_t)pb[j]; }
        } else {
            const half_t* A = (const half_t*)Ain;
            a0 = *(const f16x8*)&A[(size_t)xra * K + ko];
            a1 = *(const f16x8*)&A[(size_t)xrb * K + ko];
        }
        #pragma unroll
        for (int ct = 0; ct < 8; ct++) {
            f16x8 b = *(const f16x8*)&BT[(size_t)(ct * 16 + lr) * K + ko];
            acc[0][ct] = MFMA(a0, b, acc[0][ct]);
            acc[1][ct] = MFMA(a1, b, acc[1][ct]);
        }
    }
    // transposed epilogue: YT[g][c][i], g = r>>6, i = r&63
    #pragma unroll
    for (int rt = 0; rt < 2; rt++) {
        #pragma unroll
        for (int q = 0; q < 4; q++) {
            int r = r0 + rt * 16 + lk * 4 + q;
            int g = r >> 6, i = r & 63;
            half_t* dst = &YT[(size_t)g * 8192 + i];
            #pragma unroll
            for (int ct = 0; ct < 8; ct++)
                dst[(ct * 16 + lr) * 64] = (half_t)acc[rt][ct][q];
        }
    }
}

// ---------------------------------------------------------------------------
// k_aggA: h1 = relu(Â@Y1 + b1). One WAVE per graph, no LDS, no barriers.
// A-frags from AinG, B-frags from Y1T — both straight from global (L2/L3).
// Writes h1 [100000][128] f16 (real rows only).
// ---------------------------------------------------------------------------
__global__ __launch_bounds__(256) void k_aggA(
    const half_t* __restrict__ AinG, const half_t* __restrict__ Y1T,
    const float* __restrict__ b1, half_t* __restrict__ h1)
{
    const int t = threadIdx.x, w = t >> 6, l = t & 63;
    const int lr = l & 15, lk = l >> 4;
    const int g = blockIdx.x * 4 + w;
    const half_t* Ag = AinG + (size_t)g * 4096;
    const half_t* Yg = Y1T + (size_t)g * 8192;

    float bias[8];
    #pragma unroll
    for (int nt = 0; nt < 8; nt++) bias[nt] = b1[nt * 16 + lr];

    #pragma unroll
    for (int st = 0; st < 4; st++) {
        f16x8 a0 = *(const f16x8*)&Ag[(st * 16 + lr) * 64 + lk * 8];
        f16x8 a1 = *(const f16x8*)&Ag[(st * 16 + lr) * 64 + 32 + lk * 8];
        f32x4 acc[8] = {};
        #pragma unroll
        for (int nt = 0; nt < 8; nt++) {
            f16x8 b0 = *(const f16x8*)&Yg[(nt * 16 + lr) * 64 + lk * 8];
            f16x8 b1f = *(const f16x8*)&Yg[(nt * 16 + lr) * 64 + 32 + lk * 8];
            acc[nt] = MFMA(a0, b0, acc[nt]);
            acc[nt] = MFMA(a1, b1f, acc[nt]);
        }
        #pragma unroll
        for (int q = 0; q < 4; q++) {
            int r = st * 16 + lk * 4 + q;
            if (r < NPI) {
                half_t* dst = &h1[((size_t)g * NPI + r) * 128];
                #pragma unroll
                for (int nt = 0; nt < 8; nt++)
                    dst[nt * 16 + lr] = (half_t)fmaxf(acc[nt][q] + bias[nt], 0.f);
            }
        }
    }
}

// ---------------------------------------------------------------------------
// k_aggB: h2 = relu(Â@Y2 + b2); merged[g] = [outfeat(f16), mean_{r<50}(h2)].
// One wave per graph, no LDS, no barriers.
// ---------------------------------------------------------------------------
__global__ __launch_bounds__(256) void k_aggB(
    const half_t* __restrict__ AinG, const half_t* __restrict__ Y2T,
    const float* __restrict__ b2, const float* __restrict__ outfeat,
    half_t* __restrict__ merged)
{
    const int t = threadIdx.x, w = t >> 6, l = t & 63;
    const int lr = l & 15, lk = l >> 4;
    const int g = blockIdx.x * 4 + w;
    const half_t* Ag = AinG + (size_t)g * 4096;
    const half_t* Yg = Y2T + (size_t)g * 8192;

    float bias[8], psum[8];
    #pragma unroll
    for (int nt = 0; nt < 8; nt++) { bias[nt] = b2[nt * 16 + lr]; psum[nt] = 0.f; }

    #pragma unroll
    for (int st = 0; st < 4; st++) {
        f16x8 a0 = *(const f16x8*)&Ag[(st * 16 + lr) * 64 + lk * 8];
        f16x8 a1 = *(const f16x8*)&Ag[(st * 16 + lr) * 64 + 32 + lk * 8];
        f32x4 acc[8] = {};
        #pragma unroll
        for (int nt = 0; nt < 8; nt++) {
            f16x8 b0 = *(const f16x8*)&Yg[(nt * 16 + lr) * 64 + lk * 8];
            f16x8 b1f = *(const f16x8*)&Yg[(nt * 16 + lr) * 64 + 32 + lk * 8];
            acc[nt] = MFMA(a0, b0, acc[nt]);
            acc[nt] = MFMA(a1, b1f, acc[nt]);
        }
        #pragma unroll
        for (int nt = 0; nt < 8; nt++) {
            #pragma unroll
            for (int q = 0; q < 4; q++) {
                int r = st * 16 + lk * 4 + q;
                float v = fmaxf(acc[nt][q] + bias[nt], 0.f);
                psum[nt] += (r < NPI) ? v : 0.f;
            }
        }
    }
    // reduce over the 4 lk groups; lanes 0..15 hold col sums
    #pragma unroll
    for (int nt = 0; nt < 8; nt++) {
        psum[nt] += __shfl_xor(psum[nt], 16);
        psum[nt] += __shfl_xor(psum[nt], 32);
    }
    merged[(size_t)g * 192 + l] = (half_t)outfeat[(size_t)g * 64 + l];
    if (l < 16) {
        #pragma unroll
        for (int nt = 0; nt < 8; nt++)
            merged[(size_t)g * 192 + 64 + nt * 16 + l] =
                (half_t)(psum[nt] * (1.f / NPI));
    }
}

// ---------------------------------------------------------------------------
// Outer fused: 512 threads (8 waves x 16 rows). Â staged in LDS once. [r4]
// ---------------------------------------------------------------------------
template <int FIN, bool STAGE, bool LAST>
__device__ __forceinline__ void outer_layer(
    const half_t* AgL, const half_t* __restrict__ mg,
    const half_t* __restrict__ WT, const float* __restrict__ bias,
    half_t* bufP, half_t* bufQ, float* pool,
    int w, int lr, int lk, int t)
{
    f32x4 hacc[8] = {};
    constexpr int NCH = FIN / 64;
    #pragma unroll
    for (int ch = 0; ch < NCH; ch++) {
        if constexpr (STAGE) {
            __syncthreads();
            for (int i = t; i < 1024; i += 512) {
                int s = i >> 3, fo = (i & 7) * 8;
                f16x8 hv = {};
                if (s < NPO) hv = *(const f16x8*)&mg[(size_t)s * 192 + ch * 64 + fo];
                #pragma unroll
                for (int j = 0; j < 8; j++) lds_st1h(bufP, fo + j, s, 256, hv[j]);
            }
            __syncthreads();
        }
        const int rb = STAGE ? 0 : ch * 64;
        f32x4 tacc[4] = {};
        #pragma unroll
        for (int ks = 0; ks < 4; ks++) {
            f16x8 a = lds_ld8(AgL, w * 16 + lr, ks * 32 + lk * 8, 256);
            #pragma unroll
            for (int nt = 0; nt < 4; nt++) {
                f16x8 b = lds_ld8(bufP, rb + nt * 16 + lr, ks * 32 + lk * 8, 256);
                tacc[nt] = MFMA(a, b, tacc[nt]);
            }
        }
        #pragma unroll
        for (int nt = 0; nt < 4; nt++)
            #pragma unroll
            for (int q = 0; q < 4; q++)
                lds_st1(bufQ, w * 16 + lk * 4 + q, nt * 16 + lr, 128, tacc[nt][q]);
        #pragma unroll
        for (int ks2 = 0; ks2 < 2; ks2++) {
            f16x8 a1 = lds_ld8(bufQ, w * 16 + lr, ks2 * 32 + lk * 8, 128);
            #pragma unroll
            for (int nt = 0; nt < 8; nt++) {
                f16x8 b = *(const f16x8*)&WT[(nt * 16 + lr) * FIN + ch * 64 + ks2 * 32 + lk * 8];
                hacc[nt] = MFMA(a1, b, hacc[nt]);
            }
        }
    }
    __syncthreads();
    if constexpr (!LAST) {
        #pragma unroll
        for (int nt = 0; nt < 8; nt++) {
            int c = nt * 16 + lr;
            float bb = bias[c];
            #pragma unroll
            for (int q = 0; q < 4; q++)
                lds_st1(bufP, c, w * 16 + lk * 4 + q, 256, fmaxf(hacc[nt][q] + bb, 0.f));
        }
        __syncthreads();
    } else {
        #pragma unroll
        for (int nt = 0; nt < 8; nt++) {
            int c = nt * 16 + lr;
            float bb = bias[c];
            float ps = 0.f;
            #pragma unroll
            for (int q = 0; q < 4; q++) {
                int d = w * 16 + lk * 4 + q;
                float v = fmaxf(hacc[nt][q] + bb, 0.f);
                ps += (d < NPO) ? v : 0.f;
            }
            ps += __shfl_xor(ps, 16);
            ps += __shfl_xor(ps, 32);
            if (lk == 0) atomicAdd(&pool[c], ps);
        }
        __syncthreads();
    }
}

__global__ __launch_bounds__(512) void k_outer(
    const half_t* __restrict__ Aout, const half_t* __restrict__ merged,
    const half_t* __restrict__ WT3, const float* __restrict__ b3,
    const half_t* __restrict__ WT4, const float* __restrict__ b4,
    const half_t* __restrict__ WT5, const float* __restrict__ b5,
    const half_t* __restrict__ WT6, const float* __restrict__ b6,
    const float* __restrict__ Wc, const float* __restrict__ bc,
    float* __restrict__ out)
{
    __shared__ alignas(16) char smem[82432];
    half_t* AgL  = (half_t*)smem;             // [128][256B] swz
    half_t* bufP = (half_t*)(smem + 32768);   // [128][256B] swz (h^T)
    half_t* bufQ = (half_t*)(smem + 65536);   // [128][128B] swz (T)
    float*  pool = (float*)(smem + 81920);    // [128]

    const int g = blockIdx.x, t = threadIdx.x;
    const int w = t >> 6, l = t & 63, lr = l & 15, lk = l >> 4;
    const half_t* mg = merged + (size_t)g * NPO * 192;

    for (int i = t; i < 2048; i += 512) {
        int row = i >> 4, k0 = (i & 15) * 8;
        f16x8 v = *(const f16x8*)&Aout[(size_t)g * 16384 + row * 128 + k0];
        lds_st8(AgL, row, k0, 256, v);
    }
    if (t < 128) pool[t] = 0.f;
    __syncthreads();

    outer_layer<192, true,  false>(AgL, mg, WT3, b3, bufP, bufQ, pool, w, lr, lk, t);
    outer_layer<128, false, false>(AgL, nullptr, WT4, b4, bufP, bufQ, pool, w, lr, lk, t);
    outer_layer<128, false, false>(AgL, nullptr, WT5, b5, bufP, bufQ, pool, w, lr, lk, t);
    outer_layer<128, false, true >(AgL, nullptr, WT6, b6, bufP, bufQ, pool, w, lr, lk, t);

    if (t < NC) {
        float acc = bc[t];
        for (int k = 0; k < 128; k++)
            acc = fmaf(pool[k] * (1.f / NPO), Wc[k * NC + t], acc);
        out[g * NC + t] = acc;
    }
}

extern "C" void kernel_launch(void* const* d_in, const int* in_sizes, int n_in,
                              void* d_out, int out_size, void* d_ws, size_t ws_size,
                              hipStream_t stream)
{
    const float* X       = (const float*)d_in[0];
    const float* outfeat = (const float*)d_in[1];
    const float* iew     = (const float*)d_in[2];
    const float* oew     = (const float*)d_in[3];
    const float* W1 = (const float*)d_in[4];  const float* b1 = (const float*)d_in[5];
    const float* W2 = (const float*)d_in[6];  const float* b2 = (const float*)d_in[7];
    const float* W3 = (const float*)d_in[8];  const float* b3 = (const float*)d_in[9];
    const float* W4 = (const float*)d_in[10]; const float* b4 = (const float*)d_in[11];
    const float* W5 = (const float*)d_in[12]; const float* b5 = (const float*)d_in[13];
    const float* W6 = (const float*)d_in[14]; const float* b6 = (const float*)d_in[15];
    const float* Wc = (const float*)d_in[16]; const float* bc = (const float*)d_in[17];
    const int* isrc = (const int*)d_in[18];   const int* idst = (const int*)d_in[19];
    const int* osrc = (const int*)d_in[20];   const int* odst = (const int*)d_in[21];

    char* base = (char*)d_ws;
    half_t* WT1 = (half_t*)(base + 0);        // [128][64]
    half_t* WT2 = (half_t*)(base + 16384);    // [128][128]
    half_t* WT3 = (half_t*)(base + 49152);    // [128][192]
    half_t* WT4 = (half_t*)(base + 98304);    // [128][128]
    half_t* WT5 = (half_t*)(base + 131072);   // [128][128]
    half_t* WT6 = (half_t*)(base + 163840);   // [128][128]
    half_t* AoutG  = (half_t*)(base + 196608);    // [16][128][128]   (0.5MB)
    half_t* merged = (half_t*)(base + 720896);    // [2000][192]      (0.77MB)
    half_t* AinG   = (half_t*)(base + 1490944);   // [2000][64][64]   (16.4MB)
    half_t* YT     = (half_t*)(base + 17874944);  // [2000][128][64]  (32.8MB, Y1T then Y2T)
    half_t* h1     = (half_t*)(base + 50642944);  // [100000][128]    (25.6MB)

    k_pre<<<400, 256, 0, stream>>>(W1, W2, W3, W4, W5, W6,
                                   WT1, WT2, WT3, WT4, WT5, WT6,
                                   oew, osrc, odst, AoutG);
    k_adjI<<<N_OUT, 256, 0, stream>>>(iew, isrc, idst, AinG);
    k_gemmT<64, true><<<1000, 256, 0, stream>>>((const void*)X, WT1, YT);     // Y1T
    k_aggA<<<500, 256, 0, stream>>>(AinG, YT, b1, h1);
    k_gemmT<128, false><<<1000, 256, 0, stream>>>((const void*)h1, WT2, YT);  // Y2T
    k_aggB<<<500, 256, 0, stream>>>(AinG, YT, b2, outfeat, merged);
    k_outer<<<NB, 512, 0, stream>>>(AoutG, merged, WT3, b3, WT4, b4,
                                    WT5, b5, WT6, b6, Wc, bc, (float*)d_out);
}

// Round 8
// 150.654 us; speedup vs baseline: 1.0171x; 1.0171x over previous
//
#include <hip/hip_runtime.h>

#define NPI 50      // nodes per inner graph
#define EPI 400     // edges per inner graph
#define NPO 125     // nodes per outer graph
#define EPO 1000    // edges per outer graph
#define N_IN 100000
#define N_OUT 2000
#define NB 16       // batch graphs
#define NC 10

typedef _Float16 half_t;
typedef _Float16 f16x8 __attribute__((ext_vector_type(8)));
typedef float f32x4 __attribute__((ext_vector_type(4)));

#define MFMA(a, b, c) __builtin_amdgcn_mfma_f32_16x16x32_f16(a, b, c, 0, 0, 0)

// Swizzled LDS helpers. XOR of (row&7) into byte bits 4..6 keeps ds_read_b128
// conflict-free when 16 lanes read 16 consecutive rows.
__device__ __forceinline__ f16x8 lds_ld8(const half_t* base, int row, int k, int strideB) {
    return *(const f16x8*)((const char*)base + row * strideB + ((k * 2) ^ ((row & 7) << 4)));
}
__device__ __forceinline__ void lds_st1(half_t* base, int row, int col, int strideB, float v) {
    *(half_t*)((char*)base + row * strideB + ((col * 2) ^ ((row & 7) << 4))) = (half_t)v;
}
__device__ __forceinline__ void lds_st1h(half_t* base, int row, int col, int strideB, half_t v) {
    *(half_t*)((char*)base + row * strideB + ((col * 2) ^ ((row & 7) << 4))) = v;
}
__device__ __forceinline__ void lds_st8(half_t* base, int row, int k, int strideB, f16x8 v) {
    *(f16x8*)((char*)base + row * strideB + ((k * 2) ^ ((row & 7) << 4))) = v;
}

// ---------------------------------------------------------------------------
// k_pre: blocks 0..383 convert W1..W6 -> transposed f16; blocks 384..399 build
// dense outer adjacency Â_outer [16][128][128] f16 (row-major). [r4-proven]
// ---------------------------------------------------------------------------
__global__ __launch_bounds__(256) void k_pre(
    const float* __restrict__ W1, const float* __restrict__ W2,
    const float* __restrict__ W3, const float* __restrict__ W4,
    const float* __restrict__ W5, const float* __restrict__ W6,
    half_t* __restrict__ WT1, half_t* __restrict__ WT2,
    half_t* __restrict__ WT3, half_t* __restrict__ WT4,
    half_t* __restrict__ WT5, half_t* __restrict__ WT6,
    const float* __restrict__ ew, const int* __restrict__ esrc,
    const int* __restrict__ edst, half_t* __restrict__ Aout)
{
    __shared__ float Af[NPO * NPO];
    __shared__ int cO[NPO], cI[NPO];
    __shared__ float rso[NPO], rsi[NPO];
    const int t = threadIdx.x;

    if (blockIdx.x < 384) {
        int i = blockIdx.x * 256 + t;
        const float* src; half_t* dst; int K;
        if      (i < 8192)  { src = W1; dst = WT1; K = 64; }
        else if (i < 24576) { src = W2; dst = WT2; K = 128; i -= 8192; }
        else if (i < 49152) { src = W3; dst = WT3; K = 192; i -= 24576; }
        else if (i < 65536) { src = W4; dst = WT4; K = 128; i -= 49152; }
        else if (i < 81920) { src = W5; dst = WT5; K = 128; i -= 65536; }
        else                { src = W6; dst = WT6; K = 128; i -= 81920; }
        int c = i & 127, k = i >> 7;
        dst[c * K + k] = (half_t)src[k * 128 + c];
        return;
    }

    const int g = blockIdx.x - 384;
    const int nb = g * NPO, eb = g * EPO;
    for (int i = t; i < NPO * NPO; i += 256) Af[i] = 0.f;
    if (t < NPO) { cO[t] = 0; cI[t] = 0; }
    __syncthreads();
    for (int e = t; e < EPO; e += 256) {
        int s = esrc[eb + e] - nb, d = edst[eb + e] - nb;
        atomicAdd(&Af[d * NPO + s], ew[eb + e]);
        atomicAdd(&cO[s], 1); atomicAdd(&cI[d], 1);
    }
    __syncthreads();
    if (t < NPO) {
        rso[t] = rsqrtf((float)max(cO[t], 1));
        rsi[t] = rsqrtf((float)max(cI[t], 1));
    }
    __syncthreads();
    for (int i = t; i < 128 * 16; i += 256) {
        int d = i >> 4, s0 = (i & 15) * 8;
        f16x8 v;
        #pragma unroll
        for (int j = 0; j < 8; j++) {
            int s = s0 + j;
            float x = (d < NPO && s < NPO) ? Af[d * NPO + s] * rsi[d] * rso[s] : 0.f;
            v[j] = (half_t)x;
        }
        *(f16x8*)&Aout[(size_t)g * 16384 + d * 128 + s0] = v;
    }
}

// ---------------------------------------------------------------------------
// k_adjI: per-graph inner Â (64x64 zero-padded, normalized) -> global f16.
// ---------------------------------------------------------------------------
__global__ __launch_bounds__(256) void k_adjI(
    const float* __restrict__ ew, const int* __restrict__ esrc,
    const int* __restrict__ edst, half_t* __restrict__ AinG)
{
    __shared__ float Af[64 * 64];
    __shared__ int cO[64], cI[64];
    const int g = blockIdx.x, t = threadIdx.x;
    const int nb = g * NPI, eb = g * EPI;

    int s0e, d0e; float w0e;
    { int e = eb + t; s0e = esrc[e] - nb; d0e = edst[e] - nb; w0e = ew[e]; }
    int s1e = 0, d1e = 0; float w1e = 0.f;
    const bool e1v = (t + 256 < EPI);
    if (e1v) { int e = eb + t + 256; s1e = esrc[e] - nb; d1e = edst[e] - nb; w1e = ew[e]; }

    if (t < 64) { cO[t] = 0; cI[t] = 0; }
    for (int i = t; i < 4096; i += 256) Af[i] = 0.f;
    __syncthreads();
    atomicAdd(&Af[d0e * 64 + s0e], w0e);
    atomicAdd(&cO[s0e], 1); atomicAdd(&cI[d0e], 1);
    if (e1v) {
        atomicAdd(&Af[d1e * 64 + s1e], w1e);
        atomicAdd(&cO[s1e], 1); atomicAdd(&cI[d1e], 1);
    }
    __syncthreads();
    #pragma unroll
    for (int j = 0; j < 2; j++) {
        int id = t + j * 256;
        int row = id >> 3, k0 = (id & 7) * 8;
        float rsi_l = rsqrtf((float)max(cI[row], 1));
        f16x8 v;
        #pragma unroll
        for (int jj = 0; jj < 8; jj++)
            v[jj] = (half_t)(Af[row * 64 + k0 + jj] * rsi_l *
                             rsqrtf((float)max(cO[k0 + jj], 1)));
        *(f16x8*)&AinG[(size_t)g * 4096 + row * 64 + k0] = v;
    }
}

// ---------------------------------------------------------------------------
// k_gemmT: Y^T stored per graph as [2000][128][64]. Epilogue now stages the
// C-tile in swizzled LDS and writes YT with coalesced f16x8 vector stores
// (was: 64 scattered 2B global stores per thread — the r7 hotspot).
// ---------------------------------------------------------------------------
template <int K, bool F32IN>
__global__ __launch_bounds__(256) void k_gemmT(
    const void* __restrict__ Ain, const half_t* __restrict__ BT,
    half_t* __restrict__ YT)
{
    __shared__ alignas(16) half_t Cs[128 * 128];   // [f][local_row], swz s256
    const int t = threadIdx.x, w = t >> 6, l = t & 63;
    const int lr = l & 15, lk = l >> 4;
    const int r0 = blockIdx.x * 128 + w * 32;

    const int ra = r0 + lr, rb = r0 + 16 + lr;
    const int xra = (ra >> 6) * 50 + min(ra & 63, 49);
    const int xrb = (rb >> 6) * 50 + min(rb & 63, 49);

    f32x4 acc[2][8] = {};
    for (int ks = 0; ks < K / 32; ks++) {
        const int ko = ks * 32 + lk * 8;
        f16x8 a0, a1;
        if constexpr (F32IN) {
            const float* A = (const float*)Ain;
            const float* pa = &A[(size_t)xra * K + ko];
            const float* pb = &A[(size_t)xrb * K + ko];
            #pragma unroll
            for (int j = 0; j < 8; j++) { a0[j] = (half_t)pa[j]; a1[j] = (half_t)pb[j]; }
        } else {
            const half_t* A = (const half_t*)Ain;
            a0 = *(const f16x8*)&A[(size_t)xra * K + ko];
            a1 = *(const f16x8*)&A[(size_t)xrb * K + ko];
        }
        #pragma unroll
        for (int ct = 0; ct < 8; ct++) {
            f16x8 b = *(const f16x8*)&BT[(size_t)(ct * 16 + lr) * K + ko];
            acc[0][ct] = MFMA(a0, b, acc[0][ct]);
            acc[1][ct] = MFMA(a1, b, acc[1][ct]);
        }
    }
    // frags -> LDS [f][local_row] (scalar, swizzled)
    #pragma unroll
    for (int rt = 0; rt < 2; rt++) {
        #pragma unroll
        for (int q = 0; q < 4; q++) {
            int lrow = w * 32 + rt * 16 + lk * 4 + q;
            #pragma unroll
            for (int ct = 0; ct < 8; ct++)
                lds_st1(Cs, ct * 16 + lr, lrow, 256, acc[rt][ct][q]);
        }
    }
    __syncthreads();
    // coalesced vector writeback: YT[g][f][i0..i0+8]
    const int base_g = blockIdx.x * 2;
    #pragma unroll
    for (int j = 0; j < 8; j++) {
        int id = t + j * 256;            // 0..2047
        int f = id >> 4, hi = id & 15;
        int g01 = hi >> 3, i0 = (hi & 7) * 8;
        f16x8 v = lds_ld8(Cs, f, g01 * 64 + i0, 256);
        *(f16x8*)&YT[(size_t)(base_g + g01) * 8192 + f * 64 + i0] = v;
    }
}

// ---------------------------------------------------------------------------
// k_aggA: h1 = relu(Â@Y1 + b1). One WAVE per graph, no LDS, no barriers.
// ---------------------------------------------------------------------------
__global__ __launch_bounds__(256) void k_aggA(
    const half_t* __restrict__ AinG, const half_t* __restrict__ Y1T,
    const float* __restrict__ b1, half_t* __restrict__ h1)
{
    const int t = threadIdx.x, w = t >> 6, l = t & 63;
    const int lr = l & 15, lk = l >> 4;
    const int g = blockIdx.x * 4 + w;
    const half_t* Ag = AinG + (size_t)g * 4096;
    const half_t* Yg = Y1T + (size_t)g * 8192;

    float bias[8];
    #pragma unroll
    for (int nt = 0; nt < 8; nt++) bias[nt] = b1[nt * 16 + lr];

    #pragma unroll
    for (int st = 0; st < 4; st++) {
        f16x8 a0 = *(const f16x8*)&Ag[(st * 16 + lr) * 64 + lk * 8];
        f16x8 a1 = *(const f16x8*)&Ag[(st * 16 + lr) * 64 + 32 + lk * 8];
        f32x4 acc[8] = {};
        #pragma unroll
        for (int nt = 0; nt < 8; nt++) {
            f16x8 b0 = *(const f16x8*)&Yg[(nt * 16 + lr) * 64 + lk * 8];
            f16x8 b1f = *(const f16x8*)&Yg[(nt * 16 + lr) * 64 + 32 + lk * 8];
            acc[nt] = MFMA(a0, b0, acc[nt]);
            acc[nt] = MFMA(a1, b1f, acc[nt]);
        }
        #pragma unroll
        for (int q = 0; q < 4; q++) {
            int r = st * 16 + lk * 4 + q;
            if (r < NPI) {
                half_t* dst = &h1[((size_t)g * NPI + r) * 128];
                #pragma unroll
                for (int nt = 0; nt < 8; nt++)
                    dst[nt * 16 + lr] = (half_t)fmaxf(acc[nt][q] + bias[nt], 0.f);
            }
        }
    }
}

// ---------------------------------------------------------------------------
// k_aggB: h2 = relu(Â@Y2 + b2); merged[g] = [outfeat(f16), mean_{r<50}(h2)].
// ---------------------------------------------------------------------------
__global__ __launch_bounds__(256) void k_aggB(
    const half_t* __restrict__ AinG, const half_t* __restrict__ Y2T,
    const float* __restrict__ b2, const float* __restrict__ outfeat,
    half_t* __restrict__ merged)
{
    const int t = threadIdx.x, w = t >> 6, l = t & 63;
    const int lr = l & 15, lk = l >> 4;
    const int g = blockIdx.x * 4 + w;
    const half_t* Ag = AinG + (size_t)g * 4096;
    const half_t* Yg = Y2T + (size_t)g * 8192;

    float bias[8], psum[8];
    #pragma unroll
    for (int nt = 0; nt < 8; nt++) { bias[nt] = b2[nt * 16 + lr]; psum[nt] = 0.f; }

    #pragma unroll
    for (int st = 0; st < 4; st++) {
        f16x8 a0 = *(const f16x8*)&Ag[(st * 16 + lr) * 64 + lk * 8];
        f16x8 a1 = *(const f16x8*)&Ag[(st * 16 + lr) * 64 + 32 + lk * 8];
        f32x4 acc[8] = {};
        #pragma unroll
        for (int nt = 0; nt < 8; nt++) {
            f16x8 b0 = *(const f16x8*)&Yg[(nt * 16 + lr) * 64 + lk * 8];
            f16x8 b1f = *(const f16x8*)&Yg[(nt * 16 + lr) * 64 + 32 + lk * 8];
            acc[nt] = MFMA(a0, b0, acc[nt]);
            acc[nt] = MFMA(a1, b1f, acc[nt]);
        }
        #pragma unroll
        for (int nt = 0; nt < 8; nt++) {
            #pragma unroll
            for (int q = 0; q < 4; q++) {
                int r = st * 16 + lk * 4 + q;
                float v = fmaxf(acc[nt][q] + bias[nt], 0.f);
                psum[nt] += (r < NPI) ? v : 0.f;
            }
        }
    }
    #pragma unroll
    for (int nt = 0; nt < 8; nt++) {
        psum[nt] += __shfl_xor(psum[nt], 16);
        psum[nt] += __shfl_xor(psum[nt], 32);
    }
    merged[(size_t)g * 192 + l] = (half_t)outfeat[(size_t)g * 64 + l];
    if (l < 16) {
        #pragma unroll
        for (int nt = 0; nt < 8; nt++)
            merged[(size_t)g * 192 + 64 + nt * 16 + l] =
                (half_t)(psum[nt] * (1.f / NPI));
    }
}

// ---------------------------------------------------------------------------
// Outer fused @1024 threads: 16 waves = 8 row-tiles x 2 col-halves, 4/SIMD.
// Per-wave phase work halved vs r7's 8-wave version; barriers: T->H and
// H->next-T per chunk.
// ---------------------------------------------------------------------------
template <int FIN, bool STAGE, bool LAST>
__device__ __forceinline__ void outer_layer(
    const half_t* AgL, const half_t* __restrict__ mg,
    const half_t* __restrict__ WT, const float* __restrict__ bias,
    half_t* bufP, half_t* bufQ, float* pool,
    int wr, int wc, int lr, int lk, int t)
{
    f32x4 hacc[4] = {};
    constexpr int NCH = FIN / 64;
    #pragma unroll
    for (int ch = 0; ch < NCH; ch++) {
        if constexpr (STAGE) {
            // entry barrier contract: prior bufP readers done
            {
                int s = t >> 3, fo = (t & 7) * 8;
                f16x8 hv = {};
                if (s < NPO) hv = *(const f16x8*)&mg[(size_t)s * 192 + ch * 64 + fo];
                #pragma unroll
                for (int j = 0; j < 8; j++) lds_st1h(bufP, fo + j, s, 256, hv[j]);
            }
            __syncthreads();
        }
        const int rb = STAGE ? 0 : ch * 64;
        // T chunk = Â @ h[:, ch*64:+64]; wave computes rows wr, T-cols wc*32+..
        f32x4 tacc[2] = {};
        #pragma unroll
        for (int ks = 0; ks < 4; ks++) {
            f16x8 a = lds_ld8(AgL, wr * 16 + lr, ks * 32 + lk * 8, 256);
            #pragma unroll
            for (int nt = 0; nt < 2; nt++) {
                f16x8 b = lds_ld8(bufP, rb + wc * 32 + nt * 16 + lr, ks * 32 + lk * 8, 256);
                tacc[nt] = MFMA(a, b, tacc[nt]);
            }
        }
        #pragma unroll
        for (int nt = 0; nt < 2; nt++)
            #pragma unroll
            for (int q = 0; q < 4; q++)
                lds_st1(bufQ, wr * 16 + lk * 4 + q, wc * 32 + nt * 16 + lr, 128,
                        tacc[nt][q]);
        __syncthreads();   // both col-halves of bufQ rows visible
        // H partial: rows wr, H-cols wc*64+.., K = this chunk's 64 T-cols
        #pragma unroll
        for (int ks2 = 0; ks2 < 2; ks2++) {
            f16x8 a1 = lds_ld8(bufQ, wr * 16 + lr, ks2 * 32 + lk * 8, 128);
            #pragma unroll
            for (int nt = 0; nt < 4; nt++) {
                f16x8 b = *(const f16x8*)&WT[(size_t)(wc * 64 + nt * 16 + lr) * FIN
                                             + ch * 64 + ks2 * 32 + lk * 8];
                hacc[nt] = MFMA(a1, b, hacc[nt]);
            }
        }
        __syncthreads();   // bufQ reads done before next chunk overwrites
    }
    if constexpr (!LAST) {
        #pragma unroll
        for (int nt = 0; nt < 4; nt++) {
            int c = wc * 64 + nt * 16 + lr;
            float bb = bias[c];
            #pragma unroll
            for (int q = 0; q < 4; q++)
                lds_st1(bufP, c, wr * 16 + lk * 4 + q, 256, fmaxf(hacc[nt][q] + bb, 0.f));
        }
        __syncthreads();
    } else {
        #pragma unroll
        for (int nt = 0; nt < 4; nt++) {
            int c = wc * 64 + nt * 16 + lr;
            float bb = bias[c];
            float ps = 0.f;
            #pragma unroll
            for (int q = 0; q < 4; q++) {
                int d = wr * 16 + lk * 4 + q;
                float v = fmaxf(hacc[nt][q] + bb, 0.f);
                ps += (d < NPO) ? v : 0.f;
            }
            ps += __shfl_xor(ps, 16);
            ps += __shfl_xor(ps, 32);
            if (lk == 0) atomicAdd(&pool[c], ps);
        }
        __syncthreads();
    }
}

__global__ __launch_bounds__(1024) void k_outer(
    const half_t* __restrict__ Aout, const half_t* __restrict__ merged,
    const half_t* __restrict__ WT3, const float* __restrict__ b3,
    const half_t* __restrict__ WT4, const float* __restrict__ b4,
    const half_t* __restrict__ WT5, const float* __restrict__ b5,
    const half_t* __restrict__ WT6, const float* __restrict__ b6,
    const float* __restrict__ Wc, const float* __restrict__ bc,
    float* __restrict__ out)
{
    __shared__ alignas(16) char smem[82432];
    half_t* AgL  = (half_t*)smem;             // [128][256B] swz
    half_t* bufP = (half_t*)(smem + 32768);   // [128][256B] swz (h^T)
    half_t* bufQ = (half_t*)(smem + 65536);   // [128][128B] swz (T chunk)
    float*  pool = (float*)(smem + 81920);    // [128]

    const int g = blockIdx.x, t = threadIdx.x;
    const int w = t >> 6, l = t & 63, lr = l & 15, lk = l >> 4;
    const int wr = w & 7, wc = w >> 3;
    const half_t* mg = merged + (size_t)g * NPO * 192;

    for (int i = t; i < 2048; i += 1024) {
        int row = i >> 4, k0 = (i & 15) * 8;
        f16x8 v = *(const f16x8*)&Aout[(size_t)g * 16384 + row * 128 + k0];
        lds_st8(AgL, row, k0, 256, v);
    }
    if (t < 128) pool[t] = 0.f;
    __syncthreads();

    outer_layer<192, true,  false>(AgL, mg, WT3, b3, bufP, bufQ, pool, wr, wc, lr, lk, t);
    outer_layer<128, false, false>(AgL, nullptr, WT4, b4, bufP, bufQ, pool, wr, wc, lr, lk, t);
    outer_layer<128, false, false>(AgL, nullptr, WT5, b5, bufP, bufQ, pool, wr, wc, lr, lk, t);
    outer_layer<128, false, true >(AgL, nullptr, WT6, b6, bufP, bufQ, pool, wr, wc, lr, lk, t);

    if (t < NC) {
        float acc = bc[t];
        for (int k = 0; k < 128; k++)
            acc = fmaf(pool[k] * (1.f / NPO), Wc[k * NC + t], acc);
        out[g * NC + t] = acc;
    }
}

extern "C" void kernel_launch(void* const* d_in, const int* in_sizes, int n_in,
                              void* d_out, int out_size, void* d_ws, size_t ws_size,
                              hipStream_t stream)
{
    const float* X       = (const float*)d_in[0];
    const float* outfeat = (const float*)d_in[1];
    const float* iew     = (const float*)d_in[2];
    const float* oew     = (const float*)d_in[3];
    const float* W1 = (const float*)d_in[4];  const float* b1 = (const float*)d_in[5];
    const float* W2 = (const float*)d_in[6];  const float* b2 = (const float*)d_in[7];
    const float* W3 = (const float*)d_in[8];  const float* b3 = (const float*)d_in[9];
    const float* W4 = (const float*)d_in[10]; const float* b4 = (const float*)d_in[11];
    const float* W5 = (const float*)d_in[12]; const float* b5 = (const float*)d_in[13];
    const float* W6 = (const float*)d_in[14]; const float* b6 = (const float*)d_in[15];
    const float* Wc = (const float*)d_in[16]; const float* bc = (const float*)d_in[17];
    const int* isrc = (const int*)d_in[18];   const int* idst = (const int*)d_in[19];
    const int* osrc = (const int*)d_in[20];   const int* odst = (const int*)d_in[21];

    char* base = (char*)d_ws;
    half_t* WT1 = (half_t*)(base + 0);        // [128][64]
    half_t* WT2 = (half_t*)(base + 16384);    // [128][128]
    half_t* WT3 = (half_t*)(base + 49152);    // [128][192]
    half_t* WT4 = (half_t*)(base + 98304);    // [128][128]
    half_t* WT5 = (half_t*)(base + 131072);   // [128][128]
    half_t* WT6 = (half_t*)(base + 163840);   // [128][128]
    half_t* AoutG  = (half_t*)(base + 196608);    // [16][128][128]
    half_t* merged = (half_t*)(base + 720896);    // [2000][192]
    half_t* AinG   = (half_t*)(base + 1490944);   // [2000][64][64]
    half_t* YT     = (half_t*)(base + 17874944);  // [2000][128][64]
    half_t* h1     = (half_t*)(base + 50642944);  // [100000][128]

    k_pre<<<400, 256, 0, stream>>>(W1, W2, W3, W4, W5, W6,
                                   WT1, WT2, WT3, WT4, WT5, WT6,
                                   oew, osrc, odst, AoutG);
    k_adjI<<<N_OUT, 256, 0, stream>>>(iew, isrc, idst, AinG);
    k_gemmT<64, true><<<1000, 256, 0, stream>>>((const void*)X, WT1, YT);     // Y1T
    k_aggA<<<500, 256, 0, stream>>>(AinG, YT, b1, h1);
    k_gemmT<128, false><<<1000, 256, 0, stream>>>((const void*)h1, WT2, YT);  // Y2T
    k_aggB<<<500, 256, 0, stream>>>(AinG, YT, b2, outfeat, merged);
    k_outer<<<NB, 1024, 0, stream>>>(AoutG, merged, WT3, b3, WT4, b4,
                                     WT5, b5, WT6, b6, Wc, bc, (float*)d_out);
}

// Round 9
// 122.284 us; speedup vs baseline: 1.2531x; 1.2320x over previous
//
#include <hip/hip_runtime.h>

#define NPI 50      // nodes per inner graph
#define EPI 400     // edges per inner graph
#define NPO 125     // nodes per outer graph
#define EPO 1000    // edges per outer graph
#define N_IN 100000
#define N_OUT 2000
#define NB 16       // batch graphs
#define NC 10

typedef _Float16 half_t;
typedef _Float16 f16x8 __attribute__((ext_vector_type(8)));
typedef float f32x4 __attribute__((ext_vector_type(4)));

#define MFMA(a, b, c) __builtin_amdgcn_mfma_f32_16x16x32_f16(a, b, c, 0, 0, 0)

// Swizzled LDS helpers. XOR of (row&7) into byte bits 4..6 keeps ds_read_b128
// conflict-free when 16 lanes read 16 consecutive rows.
__device__ __forceinline__ f16x8 lds_ld8(const half_t* base, int row, int k, int strideB) {
    return *(const f16x8*)((const char*)base + row * strideB + ((k * 2) ^ ((row & 7) << 4)));
}
__device__ __forceinline__ void lds_st1(half_t* base, int row, int col, int strideB, float v) {
    *(half_t*)((char*)base + row * strideB + ((col * 2) ^ ((row & 7) << 4))) = (half_t)v;
}
__device__ __forceinline__ void lds_st1h(half_t* base, int row, int col, int strideB, half_t v) {
    *(half_t*)((char*)base + row * strideB + ((col * 2) ^ ((row & 7) << 4))) = v;
}
// per-wave scratch [16][32] f16, stride 64B, XOR (row&3)<<4
__device__ __forceinline__ f16x8 scr_ld8(const half_t* base, int row, int k) {
    return *(const f16x8*)((const char*)base + row * 64 + ((k * 2) ^ ((row & 3) << 4)));
}
__device__ __forceinline__ void scr_st1(half_t* base, int row, int col, float v) {
    *(half_t*)((char*)base + row * 64 + ((col * 2) ^ ((row & 3) << 4))) = (half_t)v;
}

// ---------------------------------------------------------------------------
// k_pre: blocks 0..383 convert W1..W6 -> transposed f16; blocks 384..399 build
// dense outer adjacency Â_outer [16][128][128] f16 (row-major). [r4-proven]
// ---------------------------------------------------------------------------
__global__ __launch_bounds__(256) void k_pre(
    const float* __restrict__ W1, const float* __restrict__ W2,
    const float* __restrict__ W3, const float* __restrict__ W4,
    const float* __restrict__ W5, const float* __restrict__ W6,
    half_t* __restrict__ WT1, half_t* __restrict__ WT2,
    half_t* __restrict__ WT3, half_t* __restrict__ WT4,
    half_t* __restrict__ WT5, half_t* __restrict__ WT6,
    const float* __restrict__ ew, const int* __restrict__ esrc,
    const int* __restrict__ edst, half_t* __restrict__ Aout)
{
    __shared__ float Af[NPO * NPO];
    __shared__ int cO[NPO], cI[NPO];
    __shared__ float rso[NPO], rsi[NPO];
    const int t = threadIdx.x;

    if (blockIdx.x < 384) {
        int i = blockIdx.x * 256 + t;
        const float* src; half_t* dst; int K;
        if      (i < 8192)  { src = W1; dst = WT1; K = 64; }
        else if (i < 24576) { src = W2; dst = WT2; K = 128; i -= 8192; }
        else if (i < 49152) { src = W3; dst = WT3; K = 192; i -= 24576; }
        else if (i < 65536) { src = W4; dst = WT4; K = 128; i -= 49152; }
        else if (i < 81920) { src = W5; dst = WT5; K = 128; i -= 65536; }
        else                { src = W6; dst = WT6; K = 128; i -= 81920; }
        int c = i & 127, k = i >> 7;
        dst[c * K + k] = (half_t)src[k * 128 + c];
        return;
    }

    const int g = blockIdx.x - 384;
    const int nb = g * NPO, eb = g * EPO;
    for (int i = t; i < NPO * NPO; i += 256) Af[i] = 0.f;
    if (t < NPO) { cO[t] = 0; cI[t] = 0; }
    __syncthreads();
    for (int e = t; e < EPO; e += 256) {
        int s = esrc[eb + e] - nb, d = edst[eb + e] - nb;
        atomicAdd(&Af[d * NPO + s], ew[eb + e]);
        atomicAdd(&cO[s], 1); atomicAdd(&cI[d], 1);
    }
    __syncthreads();
    if (t < NPO) {
        rso[t] = rsqrtf((float)max(cO[t], 1));
        rsi[t] = rsqrtf((float)max(cI[t], 1));
    }
    __syncthreads();
    for (int i = t; i < 128 * 16; i += 256) {
        int d = i >> 4, s0 = (i & 15) * 8;
        f16x8 v;
        #pragma unroll
        for (int j = 0; j < 8; j++) {
            int s = s0 + j;
            float x = (d < NPO && s < NPO) ? Af[d * NPO + s] * rsi[d] * rso[s] : 0.f;
            v[j] = (half_t)x;
        }
        *(f16x8*)&Aout[(size_t)g * 16384 + d * 128 + s0] = v;
    }
}

// ---------------------------------------------------------------------------
// Inner fused (r6-proven structure, 21KB LDS) + per-kf WT register prefetch:
// the 8 WT b-frags are loaded to registers BEFORE the T-strips so their
// global latency hides under ~400cy of LDS/MFMA work instead of stalling the
// dependent H-MFMA chain.
// ---------------------------------------------------------------------------
__global__ __launch_bounds__(256, 5) void k_inner(
    const float* __restrict__ X, const float* __restrict__ outfeat,
    const float* __restrict__ ew, const int* __restrict__ esrc,
    const int* __restrict__ edst,
    const half_t* __restrict__ WT1, const float* __restrict__ b1,
    const half_t* __restrict__ WT2, const float* __restrict__ b2,
    half_t* __restrict__ merged)
{
    __shared__ alignas(16) char smem[21504];
    half_t* R2  = (half_t*)smem;             // [128][64] f16 swz s128 (XT then h1T)
    float*  Af  = (float*)smem;              // [64][64] f32, bank-swizzled (alias)
    half_t* scr = (half_t*)(smem + 16384);   // [4 waves][16][32] f16
    float*  pool= (float*)(smem + 20480);    // [128]
    int*    cO  = (int*)(smem + 20992);      // [64]
    int*    cI  = (int*)(smem + 21248);      // [64]

    const int g = blockIdx.x, t = threadIdx.x;
    const int w = t >> 6, l = t & 63, lr = l & 15, lk = l >> 4;
    const int nb = g * NPI, eb = g * EPI;
    half_t* scrw = scr + w * 512;

    // ---- all global prefetches issued at kernel entry ----
    float ofv = (t < 64) ? outfeat[(size_t)g * 64 + t] : 0.f;
    int s0e, d0e; float w0e;
    { int e = eb + t; s0e = esrc[e] - nb; d0e = edst[e] - nb; w0e = ew[e]; }
    int s1e = 0, d1e = 0; float w1e = 0.f;
    const bool e1v = (t + 256 < EPI);
    if (e1v) { int e = eb + t + 256; s1e = esrc[e] - nb; d1e = edst[e] - nb; w1e = ew[e]; }
    // X prefetch, converted to f16 immediately (8 VGPRs held, not 16)
    const int srow = t >> 2, qc = t & 3;
    f16x8 xh0 = {}, xh1 = {};
    if (srow < NPI) {
        const float* xp = &X[(size_t)(nb + srow) * 64 + qc * 16];
        float4 a = *(const float4*)(xp + 0), b = *(const float4*)(xp + 4);
        float4 c = *(const float4*)(xp + 8), d = *(const float4*)(xp + 12);
        xh0[0]=(half_t)a.x; xh0[1]=(half_t)a.y; xh0[2]=(half_t)a.z; xh0[3]=(half_t)a.w;
        xh0[4]=(half_t)b.x; xh0[5]=(half_t)b.y; xh0[6]=(half_t)b.z; xh0[7]=(half_t)b.w;
        xh1[0]=(half_t)c.x; xh1[1]=(half_t)c.y; xh1[2]=(half_t)c.z; xh1[3]=(half_t)c.w;
        xh1[4]=(half_t)d.x; xh1[5]=(half_t)d.y; xh1[6]=(half_t)d.z; xh1[7]=(half_t)d.w;
    }

    if (t < 64) { cO[t] = 0; cI[t] = 0; }
    if (t >= 64 && t < 192) pool[t - 64] = 0.f;
    for (int i = t; i < 4096; i += 256) Af[i] = 0.f;
    __syncthreads();                                         // B1

    // edge scatter into bank-swizzled Af: element (d,s) at d*64 + (s^((d&7)<<2))
    atomicAdd(&Af[d0e * 64 + (s0e ^ ((d0e & 7) << 2))], w0e);
    atomicAdd(&cO[s0e], 1); atomicAdd(&cI[d0e], 1);
    if (e1v) {
        atomicAdd(&Af[d1e * 64 + (s1e ^ ((d1e & 7) << 2))], w1e);
        atomicAdd(&cO[s1e], 1); atomicAdd(&cI[d1e], 1);
    }
    __syncthreads();                                         // B2

    // ---- build Â A-fragments in registers: row = w*16+lr, ks in {0,1} ----
    f16x8 afr[2];
    {
        const int r = w * 16 + lr;
        const int sw = (r & 7) << 2;
        const float rsi_l = rsqrtf((float)max(cI[r], 1));
        #pragma unroll
        for (int ks = 0; ks < 2; ks++) {
            const int c0 = ks * 32 + lk * 8;
            f32x4 v0 = *(const f32x4*)&Af[r * 64 + (c0 ^ sw)];
            f32x4 v1 = *(const f32x4*)&Af[r * 64 + ((c0 + 4) ^ sw)];
            f16x8 fr;
            #pragma unroll
            for (int j = 0; j < 4; j++)
                fr[j] = (half_t)(v0[j] * rsi_l * rsqrtf((float)max(cO[c0 + j], 1)));
            #pragma unroll
            for (int j = 0; j < 4; j++)
                fr[4 + j] = (half_t)(v1[j] * rsi_l * rsqrtf((float)max(cO[c0 + 4 + j], 1)));
            afr[ks] = fr;
        }
    }
    __syncthreads();                                         // B3 (Af reads done)

    // XT[f][s] overwrites Af region; cols s>=50 zero from the {} init
    #pragma unroll
    for (int i = 0; i < 8; i++) lds_st1h(R2, qc * 16 + i, srow, 128, xh0[i]);
    #pragma unroll
    for (int i = 0; i < 8; i++) lds_st1h(R2, qc * 16 + 8 + i, srow, 128, xh1[i]);
    __syncthreads();                                         // B4

    // ---- T1 = Â@X (strip-fused) -> H1 = relu(T1@W1+b1), wave = 16 rows ----
    f32x4 hacc[8] = {};
    #pragma unroll
    for (int kf = 0; kf < 2; kf++) {
        f16x8 wb[8];
        #pragma unroll
        for (int nt = 0; nt < 8; nt++)
            wb[nt] = *(const f16x8*)&WT1[(nt * 16 + lr) * 64 + kf * 32 + lk * 8];
        #pragma unroll
        for (int j = 0; j < 2; j++) {
            const int ft = kf * 2 + j;
            f32x4 tacc = {};
            #pragma unroll
            for (int ks = 0; ks < 2; ks++) {
                f16x8 b = lds_ld8(R2, ft * 16 + lr, ks * 32 + lk * 8, 128);
                tacc = MFMA(afr[ks], b, tacc);
            }
            #pragma unroll
            for (int q = 0; q < 4; q++) scr_st1(scrw, lk * 4 + q, j * 16 + lr, tacc[q]);
        }
        f16x8 a1 = scr_ld8(scrw, lr, lk * 8);
        #pragma unroll
        for (int nt = 0; nt < 8; nt++) hacc[nt] = MFMA(a1, wb[nt], hacc[nt]);
    }
    __syncthreads();                                         // B5 (XT reads done)
    #pragma unroll
    for (int nt = 0; nt < 8; nt++) {
        int c = nt * 16 + lr;
        float bb = b1[c];
        #pragma unroll
        for (int q = 0; q < 4; q++)
            lds_st1(R2, c, w * 16 + lk * 4 + q, 128, fmaxf(hacc[nt][q] + bb, 0.f));
    }
    __syncthreads();                                         // B6

    // ---- T2 = Â@h1 (strip-fused) -> H2 = relu(T2@W2+b2) -> masked pool ----
    f32x4 h2[8] = {};
    #pragma unroll
    for (int kf = 0; kf < 4; kf++) {
        f16x8 wb[8];
        #pragma unroll
        for (int nt = 0; nt < 8; nt++)
            wb[nt] = *(const f16x8*)&WT2[(nt * 16 + lr) * 128 + kf * 32 + lk * 8];
        #pragma unroll
        for (int j = 0; j < 2; j++) {
            const int ft = kf * 2 + j;
            f32x4 tacc = {};
            #pragma unroll
            for (int ks = 0; ks < 2; ks++) {
                f16x8 b = lds_ld8(R2, ft * 16 + lr, ks * 32 + lk * 8, 128);
                tacc = MFMA(afr[ks], b, tacc);
            }
            #pragma unroll
            for (int q = 0; q < 4; q++) scr_st1(scrw, lk * 4 + q, j * 16 + lr, tacc[q]);
        }
        f16x8 a1 = scr_ld8(scrw, lr, lk * 8);
        #pragma unroll
        for (int nt = 0; nt < 8; nt++) h2[nt] = MFMA(a1, wb[nt], h2[nt]);
    }
    #pragma unroll
    for (int nt = 0; nt < 8; nt++) {
        int c = nt * 16 + lr;
        float bb = b2[c];
        float ps = 0.f;
        #pragma unroll
        for (int q = 0; q < 4; q++) {
            int m = w * 16 + lk * 4 + q;
            float v = fmaxf(h2[nt][q] + bb, 0.f);
            ps += (m < NPI) ? v : 0.f;
        }
        ps += __shfl_xor(ps, 16);
        ps += __shfl_xor(ps, 32);
        if (lk == 0) atomicAdd(&pool[c], ps);
    }
    __syncthreads();                                         // B7
    if (t < 64) merged[(size_t)g * 192 + t] = (half_t)ofv;
    else if (t < 192) merged[(size_t)g * 192 + t] = (half_t)(pool[t - 64] * (1.f / NPI));
}

// ---------------------------------------------------------------------------
// Outer fused @1024 threads: 16 waves = 8 row-tiles x 2 col-halves.
// Â in registers (loaded once from global); WT frags register-prefetched per
// chunk; stage-mg loads issued at layer entry; parallel classifier.
// ---------------------------------------------------------------------------
template <int FIN, bool STAGE, bool LAST>
__device__ __forceinline__ void outer_layer(
    const f16x8* afr, const half_t* __restrict__ mg,
    const half_t* __restrict__ WT, const float* __restrict__ bias,
    half_t* bufP, half_t* bufQ, float* pool,
    int wr, int wc, int lr, int lk, int t)
{
    f32x4 hacc[4] = {};
    constexpr int NCH = FIN / 64;
    // early-issue all stage loads for this layer (global latency covered)
    f16x8 hv[NCH];
    if constexpr (STAGE) {
        const int s = t >> 3, fo = (t & 7) * 8;
        #pragma unroll
        for (int ch = 0; ch < NCH; ch++) {
            f16x8 z = {};
            hv[ch] = (s < NPO) ? *(const f16x8*)&mg[(size_t)s * 192 + ch * 64 + fo] : z;
        }
    }
    #pragma unroll
    for (int ch = 0; ch < NCH; ch++) {
        // WT register prefetch for this chunk — issued before the T-phase so
        // the global latency hides under stage/T work (the r8 53µs pathology).
        f16x8 wtb[8];
        #pragma unroll
        for (int ks2 = 0; ks2 < 2; ks2++)
            #pragma unroll
            for (int nt = 0; nt < 4; nt++)
                wtb[ks2 * 4 + nt] = *(const f16x8*)&WT[
                    (size_t)(wc * 64 + nt * 16 + lr) * FIN + ch * 64 + ks2 * 32 + lk * 8];
        if constexpr (STAGE) {
            const int s = t >> 3, fo = (t & 7) * 8;
            #pragma unroll
            for (int j = 0; j < 8; j++) lds_st1h(bufP, fo + j, s, 256, hv[ch][j]);
            __syncthreads();
        }
        const int rb = STAGE ? 0 : ch * 64;
        // T chunk = Â @ h[:, ch*64:+64]; wave: rows wr, T-cols wc*32+..
        f32x4 tacc[2] = {};
        #pragma unroll
        for (int ks = 0; ks < 4; ks++) {
            #pragma unroll
            for (int nt = 0; nt < 2; nt++) {
                f16x8 b = lds_ld8(bufP, rb + wc * 32 + nt * 16 + lr, ks * 32 + lk * 8, 256);
                tacc[nt] = MFMA(afr[ks], b, tacc[nt]);
            }
        }
        #pragma unroll
        for (int nt = 0; nt < 2; nt++)
            #pragma unroll
            for (int q = 0; q < 4; q++)
                lds_st1(bufQ, wr * 16 + lk * 4 + q, wc * 32 + nt * 16 + lr, 128,
                        tacc[nt][q]);
        __syncthreads();   // both col-halves of bufQ rows visible
        // H partial: rows wr, H-cols wc*64+.., K = this chunk's 64 T-cols
        #pragma unroll
        for (int ks2 = 0; ks2 < 2; ks2++) {
            f16x8 a1 = lds_ld8(bufQ, wr * 16 + lr, ks2 * 32 + lk * 8, 128);
            #pragma unroll
            for (int nt = 0; nt < 4; nt++)
                hacc[nt] = MFMA(a1, wtb[ks2 * 4 + nt], hacc[nt]);
        }
        __syncthreads();   // bufQ (and stage-target bufP rows) reads done
    }
    if constexpr (!LAST) {
        #pragma unroll
        for (int nt = 0; nt < 4; nt++) {
            int c = wc * 64 + nt * 16 + lr;
            float bb = bias[c];
            #pragma unroll
            for (int q = 0; q < 4; q++)
                lds_st1(bufP, c, wr * 16 + lk * 4 + q, 256, fmaxf(hacc[nt][q] + bb, 0.f));
        }
        __syncthreads();
    } else {
        #pragma unroll
        for (int nt = 0; nt < 4; nt++) {
            int c = wc * 64 + nt * 16 + lr;
            float bb = bias[c];
            float ps = 0.f;
            #pragma unroll
            for (int q = 0; q < 4; q++) {
                int d = wr * 16 + lk * 4 + q;
                float v = fmaxf(hacc[nt][q] + bb, 0.f);
                ps += (d < NPO) ? v : 0.f;
            }
            ps += __shfl_xor(ps, 16);
            ps += __shfl_xor(ps, 32);
            if (lk == 0) atomicAdd(&pool[c], ps);
        }
        __syncthreads();
    }
}

__global__ __launch_bounds__(1024) void k_outer(
    const half_t* __restrict__ Aout, const half_t* __restrict__ merged,
    const half_t* __restrict__ WT3, const float* __restrict__ b3,
    const half_t* __restrict__ WT4, const float* __restrict__ b4,
    const half_t* __restrict__ WT5, const float* __restrict__ b5,
    const half_t* __restrict__ WT6, const float* __restrict__ b6,
    const float* __restrict__ Wc, const float* __restrict__ bc,
    float* __restrict__ out)
{
    __shared__ alignas(16) char smem[49704];
    half_t* bufP = (half_t*)smem;             // [128][256B] swz (h^T)
    half_t* bufQ = (half_t*)(smem + 32768);   // [128][128B] swz (T chunk)
    float*  pool = (float*)(smem + 49152);    // [128]
    float*  cls  = (float*)(smem + 49664);    // [10]

    const int g = blockIdx.x, t = threadIdx.x;
    const int w = t >> 6, l = t & 63, lr = l & 15, lk = l >> 4;
    const int wr = w & 7, wc = w >> 3;
    const half_t* mg = merged + (size_t)g * NPO * 192;

    // Â fragments for this wave's row-tile, loaded once from global.
    f16x8 afr[4];
    #pragma unroll
    for (int ks = 0; ks < 4; ks++)
        afr[ks] = *(const f16x8*)&Aout[(size_t)g * 16384
                                       + (wr * 16 + lr) * 128 + ks * 32 + lk * 8];
    if (t < 128) pool[t] = 0.f;
    if (t >= 128 && t < 128 + NC) cls[t - 128] = 0.f;
    __syncthreads();

    outer_layer<192, true,  false>(afr, mg, WT3, b3, bufP, bufQ, pool, wr, wc, lr, lk, t);
    outer_layer<128, false, false>(afr, nullptr, WT4, b4, bufP, bufQ, pool, wr, wc, lr, lk, t);
    outer_layer<128, false, false>(afr, nullptr, WT5, b5, bufP, bufQ, pool, wr, wc, lr, lk, t);
    outer_layer<128, false, true >(afr, nullptr, WT6, b6, bufP, bufQ, pool, wr, wc, lr, lk, t);

    // parallel classifier: 128 threads load Wc rows, shfl-reduce, LDS combine
    if (t < 128) {
        float val = pool[t] * (1.f / NPO);
        float p[NC];
        #pragma unroll
        for (int c = 0; c < NC; c++) p[c] = val * Wc[t * NC + c];
        #pragma unroll
        for (int off = 32; off >= 1; off >>= 1)
            #pragma unroll
            for (int c = 0; c < NC; c++) p[c] += __shfl_xor(p[c], off);
        if ((t & 63) == 0)
            #pragma unroll
            for (int c = 0; c < NC; c++) atomicAdd(&cls[c], p[c]);
    }
    __syncthreads();
    if (t < NC) out[g * NC + t] = cls[t] + bc[t];
}

extern "C" void kernel_launch(void* const* d_in, const int* in_sizes, int n_in,
                              void* d_out, int out_size, void* d_ws, size_t ws_size,
                              hipStream_t stream)
{
    const float* X       = (const float*)d_in[0];
    const float* outfeat = (const float*)d_in[1];
    const float* iew     = (const float*)d_in[2];
    const float* oew     = (const float*)d_in[3];
    const float* W1 = (const float*)d_in[4];  const float* b1 = (const float*)d_in[5];
    const float* W2 = (const float*)d_in[6];  const float* b2 = (const float*)d_in[7];
    const float* W3 = (const float*)d_in[8];  const float* b3 = (const float*)d_in[9];
    const float* W4 = (const float*)d_in[10]; const float* b4 = (const float*)d_in[11];
    const float* W5 = (const float*)d_in[12]; const float* b5 = (const float*)d_in[13];
    const float* W6 = (const float*)d_in[14]; const float* b6 = (const float*)d_in[15];
    const float* Wc = (const float*)d_in[16]; const float* bc = (const float*)d_in[17];
    const int* isrc = (const int*)d_in[18];   const int* idst = (const int*)d_in[19];
    const int* osrc = (const int*)d_in[20];   const int* odst = (const int*)d_in[21];

    char* base = (char*)d_ws;
    half_t* WT1 = (half_t*)(base + 0);        // [128][64]
    half_t* WT2 = (half_t*)(base + 16384);    // [128][128]
    half_t* WT3 = (half_t*)(base + 49152);    // [128][192]
    half_t* WT4 = (half_t*)(base + 98304);    // [128][128]
    half_t* WT5 = (half_t*)(base + 131072);   // [128][128]
    half_t* WT6 = (half_t*)(base + 163840);   // [128][128]
    half_t* AoutG  = (half_t*)(base + 196608);   // [16][128][128]
    half_t* merged = (half_t*)(base + 720896);   // [2000][192]

    k_pre<<<400, 256, 0, stream>>>(W1, W2, W3, W4, W5, W6,
                                   WT1, WT2, WT3, WT4, WT5, WT6,
                                   oew, osrc, odst, AoutG);
    k_inner<<<N_OUT, 256, 0, stream>>>(X, outfeat, iew, isrc, idst,
                                       WT1, b1, WT2, b2, merged);
    k_outer<<<NB, 1024, 0, stream>>>(AoutG, merged, WT3, b3, WT4, b4,
                                     WT5, b5, WT6, b6, Wc, bc, (float*)d_out);
}

// Round 10
// 120.647 us; speedup vs baseline: 1.2701x; 1.0136x over previous
//
#include <hip/hip_runtime.h>

#define NPI 50      // nodes per inner graph
#define EPI 400     // edges per inner graph
#define NPO 125     // nodes per outer graph
#define EPO 1000    // edges per outer graph
#define N_IN 100000
#define N_OUT 2000
#define NB 16       // batch graphs
#define NC 10

typedef _Float16 half_t;
typedef _Float16 f16x8 __attribute__((ext_vector_type(8)));
typedef float f32x4 __attribute__((ext_vector_type(4)));

#define MFMA(a, b, c) __builtin_amdgcn_mfma_f32_16x16x32_f16(a, b, c, 0, 0, 0)

// Swizzled LDS helpers. XOR of (row&7) into byte bits 4..6 keeps ds_read_b128
// conflict-free when 16 lanes read 16 consecutive rows.
__device__ __forceinline__ f16x8 lds_ld8(const half_t* base, int row, int k, int strideB) {
    return *(const f16x8*)((const char*)base + row * strideB + ((k * 2) ^ ((row & 7) << 4)));
}
__device__ __forceinline__ void lds_st1(half_t* base, int row, int col, int strideB, float v) {
    *(half_t*)((char*)base + row * strideB + ((col * 2) ^ ((row & 7) << 4))) = (half_t)v;
}
__device__ __forceinline__ void lds_st1h(half_t* base, int row, int col, int strideB, half_t v) {
    *(half_t*)((char*)base + row * strideB + ((col * 2) ^ ((row & 7) << 4))) = v;
}
// per-wave scratch [16][32] f16, stride 64B, XOR (row&3)<<4
__device__ __forceinline__ f16x8 scr_ld8(const half_t* base, int row, int k) {
    return *(const f16x8*)((const char*)base + row * 64 + ((k * 2) ^ ((row & 3) << 4)));
}
__device__ __forceinline__ void scr_st1(half_t* base, int row, int col, float v) {
    *(half_t*)((char*)base + row * 64 + ((col * 2) ^ ((row & 3) << 4))) = (half_t)v;
}

// ---------------------------------------------------------------------------
// k_pre: blocks 0..383 convert W1..W6 -> transposed f16; blocks 384..399 build
// dense outer adjacency Â_outer [16][128][128] f16 (row-major). [r4-proven]
// ---------------------------------------------------------------------------
__global__ __launch_bounds__(256) void k_pre(
    const float* __restrict__ W1, const float* __restrict__ W2,
    const float* __restrict__ W3, const float* __restrict__ W4,
    const float* __restrict__ W5, const float* __restrict__ W6,
    half_t* __restrict__ WT1, half_t* __restrict__ WT2,
    half_t* __restrict__ WT3, half_t* __restrict__ WT4,
    half_t* __restrict__ WT5, half_t* __restrict__ WT6,
    const float* __restrict__ ew, const int* __restrict__ esrc,
    const int* __restrict__ edst, half_t* __restrict__ Aout)
{
    __shared__ float Af[NPO * NPO];
    __shared__ int cO[NPO], cI[NPO];
    __shared__ float rso[NPO], rsi[NPO];
    const int t = threadIdx.x;

    if (blockIdx.x < 384) {
        int i = blockIdx.x * 256 + t;
        const float* src; half_t* dst; int K;
        if      (i < 8192)  { src = W1; dst = WT1; K = 64; }
        else if (i < 24576) { src = W2; dst = WT2; K = 128; i -= 8192; }
        else if (i < 49152) { src = W3; dst = WT3; K = 192; i -= 24576; }
        else if (i < 65536) { src = W4; dst = WT4; K = 128; i -= 49152; }
        else if (i < 81920) { src = W5; dst = WT5; K = 128; i -= 65536; }
        else                { src = W6; dst = WT6; K = 128; i -= 81920; }
        int c = i & 127, k = i >> 7;
        dst[c * K + k] = (half_t)src[k * 128 + c];
        return;
    }

    const int g = blockIdx.x - 384;
    const int nb = g * NPO, eb = g * EPO;
    for (int i = t; i < NPO * NPO; i += 256) Af[i] = 0.f;
    if (t < NPO) { cO[t] = 0; cI[t] = 0; }
    __syncthreads();
    for (int e = t; e < EPO; e += 256) {
        int s = esrc[eb + e] - nb, d = edst[eb + e] - nb;
        atomicAdd(&Af[d * NPO + s], ew[eb + e]);
        atomicAdd(&cO[s], 1); atomicAdd(&cI[d], 1);
    }
    __syncthreads();
    if (t < NPO) {
        rso[t] = rsqrtf((float)max(cO[t], 1));
        rsi[t] = rsqrtf((float)max(cI[t], 1));
    }
    __syncthreads();
    for (int i = t; i < 128 * 16; i += 256) {
        int d = i >> 4, s0 = (i & 15) * 8;
        f16x8 v;
        #pragma unroll
        for (int j = 0; j < 8; j++) {
            int s = s0 + j;
            float x = (d < NPO && s < NPO) ? Af[d * NPO + s] * rsi[d] * rso[s] : 0.f;
            v[j] = (half_t)x;
        }
        *(f16x8*)&Aout[(size_t)g * 16384 + d * 128 + s0] = v;
    }
}

// ---------------------------------------------------------------------------
// k_inner: ONE WAVE PER GRAPH, zero barriers. All buffers wave-private;
// within-wave LDS program order replaces __syncthreads. Block = 128 thr
// (2 graphs), 52.2KB LDS -> 3 blocks/CU = 6 independent waves/CU.
// Per-wave region (26112B):
//   [0,16K)    Af f32[64][64] (swz rows)  -> h1T f16[128][64] swz s128 (overlay)
//   [16K,24K)  XT f16[64][64] swz s128    (separate: survives st-serial T1)
//   [24K,25K)  scr [16][32] f16
//   [25K,25.5K) cO/cI int[64]
// ---------------------------------------------------------------------------
__global__ __launch_bounds__(128, 2) void k_inner(
    const float* __restrict__ X, const float* __restrict__ outfeat,
    const float* __restrict__ ew, const int* __restrict__ esrc,
    const int* __restrict__ edst,
    const half_t* __restrict__ WT1, const float* __restrict__ b1,
    const half_t* __restrict__ WT2, const float* __restrict__ b2,
    half_t* __restrict__ merged)
{
    __shared__ alignas(16) char smem[52224];
    const int t = threadIdx.x, w = t >> 6, l = t & 63;
    const int lr = l & 15, lk = l >> 4;
    const int g = blockIdx.x * 2 + w;
    char* R = smem + w * 26112;
    float*  Af   = (float*)R;
    half_t* h1T  = (half_t*)R;
    half_t* XT   = (half_t*)(R + 16384);
    half_t* scrw = (half_t*)(R + 24576);
    int*    cO   = (int*)(R + 25600);
    int*    cI   = (int*)(R + 25856);
    const int nb = g * NPI, eb = g * EPI;

    // ---- entry prefetches (independent global loads) ----
    float ofv = outfeat[(size_t)g * 64 + l];
    int se[7], de[7]; float wgt[7];
    #pragma unroll
    for (int i = 0; i < 7; i++) {
        int e = l + i * 64;
        if (e < EPI) {
            se[i] = esrc[eb + e] - nb; de[i] = edst[eb + e] - nb; wgt[i] = ew[eb + e];
        } else { se[i] = 0; de[i] = 0; wgt[i] = 0.f; }
    }
    float bb1[8], bb2[8];
    #pragma unroll
    for (int nt = 0; nt < 8; nt++) { bb1[nt] = b1[nt * 16 + lr]; bb2[nt] = b2[nt * 16 + lr]; }

    // ---- zero Af + counts, then edge scatter (wave-private, in-order) ----
    cO[l] = 0; cI[l] = 0;
    #pragma unroll
    for (int i = 0; i < 16; i++)
        *(f32x4*)&Af[(i * 64 + l) * 4] = (f32x4){0.f, 0.f, 0.f, 0.f};
    #pragma unroll
    for (int i = 0; i < 7; i++) {
        if (l + i * 64 < EPI) {
            atomicAdd(&Af[de[i] * 64 + (se[i] ^ ((de[i] & 7) << 2))], wgt[i]);
            atomicAdd(&cO[se[i]], 1); atomicAdd(&cI[de[i]], 1);
        }
    }

    // ---- per-lane rso for the k-columns this lane touches (indep of st) ----
    float rso8[2][8];
    #pragma unroll
    for (int ks = 0; ks < 2; ks++)
        #pragma unroll
        for (int j = 0; j < 8; j++)
            rso8[ks][j] = rsqrtf((float)max(cO[ks * 32 + lk * 8 + j], 1));

    // ---- build Â A-fragments for all 4 row-tiles (32 VGPR) ----
    f16x8 afr[4][2];
    #pragma unroll
    for (int st = 0; st < 4; st++) {
        const int r = st * 16 + lr;
        const int sw = (r & 7) << 2;
        const float rsi_l = rsqrtf((float)max(cI[r], 1));
        #pragma unroll
        for (int ks = 0; ks < 2; ks++) {
            const int c0 = ks * 32 + lk * 8;
            f32x4 v0 = *(const f32x4*)&Af[r * 64 + (c0 ^ sw)];
            f32x4 v1 = *(const f32x4*)&Af[r * 64 + ((c0 + 4) ^ sw)];
            f16x8 fr;
            #pragma unroll
            for (int j = 0; j < 4; j++) fr[j] = (half_t)(v0[j] * rsi_l * rso8[ks][j]);
            #pragma unroll
            for (int j = 0; j < 4; j++) fr[4 + j] = (half_t)(v1[j] * rsi_l * rso8[ks][4 + j]);
            afr[st][ks] = fr;
        }
    }

    // ---- XT: zero pad cols, then X^T f16 (Af dead; XT is separate region) ----
    #pragma unroll
    for (int i = 0; i < 8; i++)
        *(f32x4*)((char*)XT + (i * 64 + l) * 16) = (f32x4){0.f, 0.f, 0.f, 0.f};
    for (int i = l; i < NPI * 16; i += 64) {
        int row = i >> 4, c4 = (i & 15) * 4;
        float4 xv = *(const float4*)&X[(size_t)(nb + row) * 64 + c4];
        lds_st1h(XT, c4 + 0, row, 128, (half_t)xv.x);
        lds_st1h(XT, c4 + 1, row, 128, (half_t)xv.y);
        lds_st1h(XT, c4 + 2, row, 128, (half_t)xv.z);
        lds_st1h(XT, c4 + 3, row, 128, (half_t)xv.w);
    }

    // ---- T1 = Â@X -> H1 = relu(T1@W1+b1) -> h1T, serial over 4 row-tiles ----
    #pragma unroll
    for (int st = 0; st < 4; st++) {
        f32x4 hacc[8] = {};
        #pragma unroll
        for (int kf = 0; kf < 2; kf++) {
            f16x8 wb[8];
            #pragma unroll
            for (int nt = 0; nt < 8; nt++)
                wb[nt] = *(const f16x8*)&WT1[(nt * 16 + lr) * 64 + kf * 32 + lk * 8];
            #pragma unroll
            for (int j = 0; j < 2; j++) {
                const int ft = kf * 2 + j;
                f32x4 tacc = {};
                #pragma unroll
                for (int ks = 0; ks < 2; ks++) {
                    f16x8 b = lds_ld8(XT, ft * 16 + lr, ks * 32 + lk * 8, 128);
                    tacc = MFMA(afr[st][ks], b, tacc);
                }
                #pragma unroll
                for (int q = 0; q < 4; q++) scr_st1(scrw, lk * 4 + q, j * 16 + lr, tacc[q]);
            }
            f16x8 a1 = scr_ld8(scrw, lr, lk * 8);
            #pragma unroll
            for (int nt = 0; nt < 8; nt++) hacc[nt] = MFMA(a1, wb[nt], hacc[nt]);
        }
        #pragma unroll
        for (int nt = 0; nt < 8; nt++) {
            int c = nt * 16 + lr;
            #pragma unroll
            for (int q = 0; q < 4; q++)
                lds_st1(h1T, c, st * 16 + lk * 4 + q, 128,
                        fmaxf(hacc[nt][q] + bb1[nt], 0.f));
        }
    }

    // ---- T2 = Â@h1 -> H2 = relu(T2@W2+b2) -> masked column-sum (pool) ----
    float psum[8];
    #pragma unroll
    for (int nt = 0; nt < 8; nt++) psum[nt] = 0.f;
    #pragma unroll
    for (int st = 0; st < 4; st++) {
        f32x4 h2acc[8] = {};
        #pragma unroll
        for (int kf = 0; kf < 4; kf++) {
            f16x8 wb[8];
            #pragma unroll
            for (int nt = 0; nt < 8; nt++)
                wb[nt] = *(const f16x8*)&WT2[(nt * 16 + lr) * 128 + kf * 32 + lk * 8];
            #pragma unroll
            for (int j = 0; j < 2; j++) {
                const int ft = kf * 2 + j;
                f32x4 tacc = {};
                #pragma unroll
                for (int ks = 0; ks < 2; ks++) {
                    f16x8 b = lds_ld8(h1T, ft * 16 + lr, ks * 32 + lk * 8, 128);
                    tacc = MFMA(afr[st][ks], b, tacc);
                }
                #pragma unroll
                for (int q = 0; q < 4; q++) scr_st1(scrw, lk * 4 + q, j * 16 + lr, tacc[q]);
            }
            f16x8 a1 = scr_ld8(scrw, lr, lk * 8);
            #pragma unroll
            for (int nt = 0; nt < 8; nt++) h2acc[nt] = MFMA(a1, wb[nt], h2acc[nt]);
        }
        #pragma unroll
        for (int nt = 0; nt < 8; nt++) {
            #pragma unroll
            for (int q = 0; q < 4; q++) {
                int r = st * 16 + lk * 4 + q;
                float v = fmaxf(h2acc[nt][q] + bb2[nt], 0.f);
                psum[nt] += (r < NPI) ? v : 0.f;
            }
        }
    }
    #pragma unroll
    for (int nt = 0; nt < 8; nt++) {
        psum[nt] += __shfl_xor(psum[nt], 16);
        psum[nt] += __shfl_xor(psum[nt], 32);
    }
    merged[(size_t)g * 192 + l] = (half_t)ofv;
    if (l < 16) {
        #pragma unroll
        for (int nt = 0; nt < 8; nt++)
            merged[(size_t)g * 192 + 64 + nt * 16 + l] = (half_t)(psum[nt] * (1.f / NPI));
    }
}

// ---------------------------------------------------------------------------
// Outer fused @1024 threads [r9-proven]: Â in registers, WT register-prefetch,
// early stage loads, parallel classifier.
// ---------------------------------------------------------------------------
template <int FIN, bool STAGE, bool LAST>
__device__ __forceinline__ void outer_layer(
    const f16x8* afr, const half_t* __restrict__ mg,
    const half_t* __restrict__ WT, const float* __restrict__ bias,
    half_t* bufP, half_t* bufQ, float* pool,
    int wr, int wc, int lr, int lk, int t)
{
    f32x4 hacc[4] = {};
    constexpr int NCH = FIN / 64;
    f16x8 hv[NCH];
    if constexpr (STAGE) {
        const int s = t >> 3, fo = (t & 7) * 8;
        #pragma unroll
        for (int ch = 0; ch < NCH; ch++) {
            f16x8 z = {};
            hv[ch] = (s < NPO) ? *(const f16x8*)&mg[(size_t)s * 192 + ch * 64 + fo] : z;
        }
    }
    #pragma unroll
    for (int ch = 0; ch < NCH; ch++) {
        f16x8 wtb[8];
        #pragma unroll
        for (int ks2 = 0; ks2 < 2; ks2++)
            #pragma unroll
            for (int nt = 0; nt < 4; nt++)
                wtb[ks2 * 4 + nt] = *(const f16x8*)&WT[
                    (size_t)(wc * 64 + nt * 16 + lr) * FIN + ch * 64 + ks2 * 32 + lk * 8];
        if constexpr (STAGE) {
            const int s = t >> 3, fo = (t & 7) * 8;
            #pragma unroll
            for (int j = 0; j < 8; j++) lds_st1h(bufP, fo + j, s, 256, hv[ch][j]);
            __syncthreads();
        }
        const int rb = STAGE ? 0 : ch * 64;
        f32x4 tacc[2] = {};
        #pragma unroll
        for (int ks = 0; ks < 4; ks++) {
            #pragma unroll
            for (int nt = 0; nt < 2; nt++) {
                f16x8 b = lds_ld8(bufP, rb + wc * 32 + nt * 16 + lr, ks * 32 + lk * 8, 256);
                tacc[nt] = MFMA(afr[ks], b, tacc[nt]);
            }
        }
        #pragma unroll
        for (int nt = 0; nt < 2; nt++)
            #pragma unroll
            for (int q = 0; q < 4; q++)
                lds_st1(bufQ, wr * 16 + lk * 4 + q, wc * 32 + nt * 16 + lr, 128,
                        tacc[nt][q]);
        __syncthreads();
        #pragma unroll
        for (int ks2 = 0; ks2 < 2; ks2++) {
            f16x8 a1 = lds_ld8(bufQ, wr * 16 + lr, ks2 * 32 + lk * 8, 128);
            #pragma unroll
            for (int nt = 0; nt < 4; nt++)
                hacc[nt] = MFMA(a1, wtb[ks2 * 4 + nt], hacc[nt]);
        }
        __syncthreads();
    }
    if constexpr (!LAST) {
        #pragma unroll
        for (int nt = 0; nt < 4; nt++) {
            int c = wc * 64 + nt * 16 + lr;
            float bb = bias[c];
            #pragma unroll
            for (int q = 0; q < 4; q++)
                lds_st1(bufP, c, wr * 16 + lk * 4 + q, 256, fmaxf(hacc[nt][q] + bb, 0.f));
        }
        __syncthreads();
    } else {
        #pragma unroll
        for (int nt = 0; nt < 4; nt++) {
            int c = wc * 64 + nt * 16 + lr;
            float bb = bias[c];
            float ps = 0.f;
            #pragma unroll
            for (int q = 0; q < 4; q++) {
                int d = wr * 16 + lk * 4 + q;
                float v = fmaxf(hacc[nt][q] + bb, 0.f);
                ps += (d < NPO) ? v : 0.f;
            }
            ps += __shfl_xor(ps, 16);
            ps += __shfl_xor(ps, 32);
            if (lk == 0) atomicAdd(&pool[c], ps);
        }
        __syncthreads();
    }
}

__global__ __launch_bounds__(1024) void k_outer(
    const half_t* __restrict__ Aout, const half_t* __restrict__ merged,
    const half_t* __restrict__ WT3, const float* __restrict__ b3,
    const half_t* __restrict__ WT4, const float* __restrict__ b4,
    const half_t* __restrict__ WT5, const float* __restrict__ b5,
    const half_t* __restrict__ WT6, const float* __restrict__ b6,
    const float* __restrict__ Wc, const float* __restrict__ bc,
    float* __restrict__ out)
{
    __shared__ alignas(16) char smem[49704];
    half_t* bufP = (half_t*)smem;             // [128][256B] swz (h^T)
    half_t* bufQ = (half_t*)(smem + 32768);   // [128][128B] swz (T chunk)
    float*  pool = (float*)(smem + 49152);    // [128]
    float*  cls  = (float*)(smem + 49664);    // [10]

    const int g = blockIdx.x, t = threadIdx.x;
    const int w = t >> 6, l = t & 63, lr = l & 15, lk = l >> 4;
    const int wr = w & 7, wc = w >> 3;
    const half_t* mg = merged + (size_t)g * NPO * 192;

    f16x8 afr[4];
    #pragma unroll
    for (int ks = 0; ks < 4; ks++)
        afr[ks] = *(const f16x8*)&Aout[(size_t)g * 16384
                                       + (wr * 16 + lr) * 128 + ks * 32 + lk * 8];
    if (t < 128) pool[t] = 0.f;
    if (t >= 128 && t < 128 + NC) cls[t - 128] = 0.f;
    __syncthreads();

    outer_layer<192, true,  false>(afr, mg, WT3, b3, bufP, bufQ, pool, wr, wc, lr, lk, t);
    outer_layer<128, false, false>(afr, nullptr, WT4, b4, bufP, bufQ, pool, wr, wc, lr, lk, t);
    outer_layer<128, false, false>(afr, nullptr, WT5, b5, bufP, bufQ, pool, wr, wc, lr, lk, t);
    outer_layer<128, false, true >(afr, nullptr, WT6, b6, bufP, bufQ, pool, wr, wc, lr, lk, t);

    if (t < 128) {
        float val = pool[t] * (1.f / NPO);
        float p[NC];
        #pragma unroll
        for (int c = 0; c < NC; c++) p[c] = val * Wc[t * NC + c];
        #pragma unroll
        for (int off = 32; off >= 1; off >>= 1)
            #pragma unroll
            for (int c = 0; c < NC; c++) p[c] += __shfl_xor(p[c], off);
        if ((t & 63) == 0)
            #pragma unroll
            for (int c = 0; c < NC; c++) atomicAdd(&cls[c], p[c]);
    }
    __syncthreads();
    if (t < NC) out[g * NC + t] = cls[t] + bc[t];
}

extern "C" void kernel_launch(void* const* d_in, const int* in_sizes, int n_in,
                              void* d_out, int out_size, void* d_ws, size_t ws_size,
                              hipStream_t stream)
{
    const float* X       = (const float*)d_in[0];
    const float* outfeat = (const float*)d_in[1];
    const float* iew     = (const float*)d_in[2];
    const float* oew     = (const float*)d_in[3];
    const float* W1 = (const float*)d_in[4];  const float* b1 = (const float*)d_in[5];
    const float* W2 = (const float*)d_in[6];  const float* b2 = (const float*)d_in[7];
    const float* W3 = (const float*)d_in[8];  const float* b3 = (const float*)d_in[9];
    const float* W4 = (const float*)d_in[10]; const float* b4 = (const float*)d_in[11];
    const float* W5 = (const float*)d_in[12]; const float* b5 = (const float*)d_in[13];
    const float* W6 = (const float*)d_in[14]; const float* b6 = (const float*)d_in[15];
    const float* Wc = (const float*)d_in[16]; const float* bc = (const float*)d_in[17];
    const int* isrc = (const int*)d_in[18];   const int* idst = (const int*)d_in[19];
    const int* osrc = (const int*)d_in[20];   const int* odst = (const int*)d_in[21];

    char* base = (char*)d_ws;
    half_t* WT1 = (half_t*)(base + 0);        // [128][64]
    half_t* WT2 = (half_t*)(base + 16384);    // [128][128]
    half_t* WT3 = (half_t*)(base + 49152);    // [128][192]
    half_t* WT4 = (half_t*)(base + 98304);    // [128][128]
    half_t* WT5 = (half_t*)(base + 131072);   // [128][128]
    half_t* WT6 = (half_t*)(base + 163840);   // [128][128]
    half_t* AoutG  = (half_t*)(base + 196608);   // [16][128][128]
    half_t* merged = (half_t*)(base + 720896);   // [2000][192]

    k_pre<<<400, 256, 0, stream>>>(W1, W2, W3, W4, W5, W6,
                                   WT1, WT2, WT3, WT4, WT5, WT6,
                                   oew, osrc, odst, AoutG);
    k_inner<<<N_OUT / 2, 128, 0, stream>>>(X, outfeat, iew, isrc, idst,
                                           WT1, b1, WT2, b2, merged);
    k_outer<<<NB, 1024, 0, stream>>>(AoutG, merged, WT3, b3, WT4, b4,
                                     WT5, b5, WT6, b6, Wc, bc, (float*)d_out);
}